// Round 6
// baseline (141.822 us; speedup 1.0000x reference)
//
#include <hip/hip_runtime.h>
#include <hip/hip_bf16.h>

// Chamfer distance, B=4, N=M=8192, D=3, fp32.
// d2(p,t) = |p|^2 + (|t|^2 - 2 p.t), |p|^2 added in epilogue.
//
// Evidence so far:
//  r1: LDS-broadcast loop = 93% VALUBusy (latency hideable) but compiler
//      rerolled (VGPR 28) => 2x instructions.
//  r3/r4: serial agent-scope-load tail ran ~40-70us SOLO (occupancy 8.8%).
//  r5: wave-uniform s_loads miss XCD-L2 (~500cyc, no pipelining) => 60us stall.
// Round 6 = r1's LDS loop + explicit scalar q regs (no reroll) + scalar fmaf
// only (no v2f) + r5's coalesced plain-load tail + single memset init.
// 4 DB points/iter: 12 fma + 4 min per query = 4 VALU/pair; broadcast
// ds_read_b128 x4 per 256 VALU cycles; prefetch distance >> 120cyc latency.

#define T 256      // threads per block
#define Q 8        // query points per thread
#define S 16       // db splits
#define CH (8192 / S)          // 512 db points per block
#define NPTS 8192
#define NCOMBO 8               // 2 directions x 4 batches
#define QSL (NPTS / (T * Q))   // 4 query slices
#define NB (NCOMBO * QSL * S)  // 512 blocks
#define CINIT 0x7F7F7F7Fu      // counter init from the 0x7F memset

#define FOR8(OP) OP(0) OP(1) OP(2) OP(3) OP(4) OP(5) OP(6) OP(7)

__global__ __launch_bounds__(T) void chamfer_fused(
    const float* __restrict__ pred, const float* __restrict__ target,
    unsigned int* __restrict__ partmin, unsigned int* __restrict__ counter,
    const float* __restrict__ bpp, const float* __restrict__ lamda,
    float* __restrict__ out)
{
    __shared__ float4 db[CH + 4];   // +4: prefetch overrun pad

    const int bid   = blockIdx.x;
    const int dbc   = bid & (S - 1);          // 4 bits
    const int qc    = (bid >> 4) & (QSL - 1); // 2 bits
    const int combo = bid >> 6;               // 0..7
    const int dir   = combo & 1;
    const int b     = combo >> 1;

    const float* qptr = (dir == 0 ? pred : target) + (size_t)b * NPTS * 3;
    const float* dptr = (dir == 0 ? target : pred) + (size_t)b * NPTS * 3;
    const int tid = threadIdx.x;

    // --- stage db chunk into LDS, transformed: (-2x, -2y, -2z, |t|^2) ---
    for (int p = tid; p < CH; p += T) {
        int gj = dbc * CH + p;
        float x = dptr[gj * 3 + 0];
        float y = dptr[gj * 3 + 1];
        float z = dptr[gj * 3 + 2];
        db[p] = make_float4(-2.f * x, -2.f * y, -2.f * z,
                            fmaf(x, x, fmaf(y, y, z * z)));
    }
    if (tid < 4)   // pad: huge (-2x etc = 0, w = +big) so mins unaffected
        db[CH + tid] = make_float4(0.f, 0.f, 0.f, 3.0e38f);

    // --- load Q query points into explicit scalar registers ---
    const int qbase = qc * (T * Q) + tid;
#define LOADQ(k) \
    const int   qi##k = qbase + (k) * T; \
    const float qx##k = qptr[qi##k * 3 + 0]; \
    const float qy##k = qptr[qi##k * 3 + 1]; \
    const float qz##k = qptr[qi##k * 3 + 2]; \
    float m##k = 3.4e38f;
    FOR8(LOADQ)
#undef LOADQ

    __syncthreads();

    // --- main loop: 4 db points/iter, 1-deep prefetch, broadcast reads ---
    float4 c0 = db[0], c1 = db[1], c2 = db[2], c3 = db[3];
    for (int j = 0; j < CH; j += 4) {
        float4 n0 = db[j + 4], n1 = db[j + 5],
               n2 = db[j + 6], n3 = db[j + 7];
#define BODY(k) { \
        float s0 = fmaf(c0.x, qx##k, fmaf(c0.y, qy##k, fmaf(c0.z, qz##k, c0.w))); \
        float s1 = fmaf(c1.x, qx##k, fmaf(c1.y, qy##k, fmaf(c1.z, qz##k, c1.w))); \
        float s2 = fmaf(c2.x, qx##k, fmaf(c2.y, qy##k, fmaf(c2.z, qz##k, c2.w))); \
        float s3 = fmaf(c3.x, qx##k, fmaf(c3.y, qy##k, fmaf(c3.z, qz##k, c3.w))); \
        m##k = fminf(m##k, fminf(fminf(s0, s1), fminf(s2, s3))); }
        FOR8(BODY)
#undef BODY
        c0 = n0; c1 = n1; c2 = n2; c3 = n3;
    }

    // --- epilogue: add |q|^2, clamp >= 0, atomicMin on bit pattern ---
#define EPI(k) { \
    float qq = fmaf(qx##k, qx##k, fmaf(qy##k, qy##k, qz##k * qz##k)); \
    float d2 = fmaxf(m##k + qq, 0.0f); \
    atomicMin(&partmin[combo * NPTS + qi##k], __float_as_uint(d2)); }
    FOR8(EPI)
#undef EPI

    // --- completion protocol ---
    __threadfence();      // drain our atomicMins to the coherence point
    __syncthreads();
    __shared__ int lastFlag;
    if (tid == 0) {
        unsigned prev = __hip_atomic_fetch_add(counter, 1u, __ATOMIC_ACQ_REL,
                                               __HIP_MEMORY_SCOPE_AGENT);
        lastFlag = (prev == CINIT + (unsigned)(NB - 1));
    }
    __syncthreads();

    // --- last block: acquire (invalidates L1), plain coalesced reduce ---
    if (lastFlag) {
        (void)__hip_atomic_load(counter, __ATOMIC_ACQUIRE,
                                __HIP_MEMORY_SCOPE_AGENT);
        const float4* pm4 = (const float4*)partmin;
        float ssum = 0.f;
#pragma unroll
        for (int it = 0; it < (NCOMBO * NPTS / 4) / T; ++it) {   // 64 iters
            float4 v = pm4[(size_t)it * T + tid];
            ssum += (v.x + v.y) + (v.z + v.w);
        }
#pragma unroll
        for (int off = 32; off; off >>= 1)
            ssum += __shfl_down(ssum, off, 64);
        __shared__ float red[4];
        int lane = tid & 63, wid = tid >> 6;
        if (lane == 0) red[wid] = ssum;
        __syncthreads();
        if (tid == 0)
            out[0] = (red[0] + red[1] + red[2] + red[3]) * (1.f / 32768.f)
                     + lamda[0] * bpp[0];
    }
}

extern "C" void kernel_launch(void* const* d_in, const int* in_sizes, int n_in,
                              void* d_out, int out_size, void* d_ws, size_t ws_size,
                              hipStream_t stream) {
    const float* pred   = (const float*)d_in[0];
    const float* target = (const float*)d_in[1];
    const float* bpp    = (const float*)d_in[2];
    const float* lamda  = (const float*)d_in[3];
    unsigned int* partmin = (unsigned int*)d_ws;
    unsigned int* counter = partmin + NCOMBO * NPTS;

    // One memset: partmin -> +3.39e38 bitpattern, counter -> CINIT
    (void)hipMemsetAsync(partmin, 0x7F,
                         ((size_t)NCOMBO * NPTS + 1) * sizeof(unsigned), stream);

    chamfer_fused<<<NB, T, 0, stream>>>(pred, target, partmin, counter,
                                        bpp, lamda, (float*)d_out);
}